// Round 3
// baseline (214.165 us; speedup 1.0000x reference)
//
#include <hip/hip_runtime.h>

// Problem constants (match reference)
#define BB 32
#define TT 200
#define RR 4096
#define CC 81
#define IOU_THRESH 0.7f
#define RED 16.0f

#define BLK 256
#define NBLOCKS (BB * (RR / BLK))   // 32 * 16 = 512

// ws layout (floats): [0]=npos, [1]=sum_ce, [2]=sum_acc, [3]=sum_reg, [4]=block counter (uint)
__global__ __launch_bounds__(BLK) void rcnn_main_kernel(
    const float* __restrict__ nms_reg,   // [B,R,4]
    const float* __restrict__ rcnn_reg,  // [B,R,4]
    const float* __restrict__ rcnn_cls,  // [B,R,C]
    const float* __restrict__ bboxes,    // [B,T,4]
    const int*   __restrict__ classes,   // [B,T]
    float* __restrict__ ws,
    float* __restrict__ out)
{
    __shared__ float s_red[4][4];   // [wave][component]

    const int tid  = threadIdx.x;
    const int lane = tid & 63;
    const int blocks_per_b = RR / BLK;              // 16
    const int b = blockIdx.x / blocks_per_b;
    const int r = (blockIdx.x % blocks_per_b) * BLK + tid;
    const long gid = (long)b * RR + r;

    // Coalesced per-lane prefetches (consumed late -> latency hidden by argmax loop)
    const float4 pr = ((const float4*)rcnn_reg)[gid];   // predicted deltas
    const float4 a  = ((const float4*)nms_reg)[gid];    // proposal box
    const float area_a = (a.z - a.x) * (a.w - a.y);

    // GT boxes for this batch: wave-uniform scalar loads (scalar cache, no LDS/VMEM)
    const float4* __restrict__ gbox = (const float4*)(bboxes + (long)b * TT * 4);

    // Rational running-argmax (no divide): best iou = bn/bd.
    float bn = -1.0f, bd = 1.0f;
    int   bt = 0;
    #pragma unroll 8
    for (int t = 0; t < TT; ++t) {
        const int tu = __builtin_amdgcn_readfirstlane(t);  // force uniform -> s_load
        const float4 g = gbox[tu];
        const float it = fmaxf(a.x, g.x);
        const float il = fmaxf(a.y, g.y);
        const float ib = fminf(a.z, g.z);
        const float ir = fminf(a.w, g.w);
        const float inter = fmaxf(ib - it, 0.0f) * fmaxf(ir - il, 0.0f);
        const float uni   = area_a + (g.z - g.x) * (g.w - g.y) - inter;
        // inter/uni > bn/bd  <=>  inter*bd > bn*uni   (uni,bd > 0); strict > = first max
        const bool better = inter * bd > bn * uni;
        bn = better ? inter : bn;
        bd = better ? uni   : bd;
        bt = better ? t     : bt;
    }

    float pos = 0.0f, ce = 0.0f, acc = 0.0f, reg = 0.0f;
    // mask: iou > 0.7  <=>  inter > 0.7 * union
    if (bn > IOU_THRESH * bd) pos = 1.0f;

    // ---- wave-cooperative CE/acc/reg over the ~3 positive lanes per wave ----
    unsigned long long pm = __ballot(pos > 0.5f);
    const float* __restrict__ clsbase = rcnn_cls + (long)b * RR * CC;
    const int r_wave0 = r & ~63;
    while (pm) {
        const int j = __ffsll(pm) - 1;
        pm &= pm - 1;
        const int r_j  = r_wave0 + j;
        const int bt_j = __shfl(bt, j);
        const int cls_j = classes[b * TT + bt_j];   // uniform -> scalar load
        const float4 gj = gbox[bt_j];               // uniform -> scalar load
        const float* row = clsbase + (long)r_j * CC;

        // Coalesced row read, kept in registers (read once)
        const float x0 = row[lane];
        const float x1 = (lane < CC - 64) ? row[64 + lane] : -INFINITY;

        // max + first-argmax butterfly across the wave
        float mv = fmaxf(x0, x1);
        int   mi = (x1 > x0) ? 64 + lane : lane;    // strict >: lower index wins ties
        #pragma unroll
        for (int off = 1; off < 64; off <<= 1) {
            const float ov = __shfl_xor(mv, off);
            const int   oi = __shfl_xor(mi, off);
            if (ov > mv || (ov == mv && oi < mi)) { mv = ov; mi = oi; }
        }
        // sum of exp
        float s = __expf(x0 - mv) + ((lane < CC - 64) ? __expf(x1 - mv) : 0.0f);
        #pragma unroll
        for (int off = 1; off < 64; off <<= 1) s += __shfl_xor(s, off);
        // logit at target class (uniform branch: cls_j is wave-uniform)
        const float xc = (cls_j < 64) ? __shfl(x0, cls_j) : __shfl(x1, cls_j - 64);

        if (lane == j) {
            ce  += mv + __logf(s) - xc;
            acc += (mi == cls_j) ? 1.0f : 0.0f;

            // ---- regression target + SmoothL1 (gj is uniform/SGPR) ----
            const float rt = rintf(gj.x / RED) * RED;  // round-half-even == jnp.round
            const float rl = rintf(gj.y / RED) * RED;
            const float rb = rintf(gj.z / RED) * RED;
            const float rr = rintf(gj.w / RED) * RED;
            float h = rb - rt; if (h == 0.0f) h = 1.0f;
            float w = rr - rl; if (w == 0.0f) w = 1.0f;
            const float d0 = fabsf(pr.x - (gj.x - rt) / h);
            const float d1 = fabsf(pr.y - (gj.y - rl) / w);
            const float d2 = fabsf(pr.z - (gj.z - rb) / h);
            const float d3 = fabsf(pr.w - (gj.w - rr) / w);
            reg += (d0 < 1.0f) ? 0.5f * d0 * d0 : d0 - 0.5f;
            reg += (d1 < 1.0f) ? 0.5f * d1 * d1 : d1 - 0.5f;
            reg += (d2 < 1.0f) ? 0.5f * d2 * d2 : d2 - 0.5f;
            reg += (d3 < 1.0f) ? 0.5f * d3 * d3 : d3 - 0.5f;
        }
    }

    // ---- wave (64-lane) shuffle reduction ----
    #pragma unroll
    for (int off = 32; off > 0; off >>= 1) {
        pos += __shfl_down(pos, off);
        ce  += __shfl_down(ce,  off);
        acc += __shfl_down(acc, off);
        reg += __shfl_down(reg, off);
    }
    const int wave = tid >> 6;
    if (lane == 0) {
        s_red[wave][0] = pos;
        s_red[wave][1] = ce;
        s_red[wave][2] = acc;
        s_red[wave][3] = reg;
    }
    __syncthreads();
    if (tid == 0) {
        float P = 0.0f, E = 0.0f, A = 0.0f, G = 0.0f;
        #pragma unroll
        for (int v = 0; v < 4; ++v) {
            P += s_red[v][0];
            E += s_red[v][1];
            A += s_red[v][2];
            G += s_red[v][3];
        }
        atomicAdd(&ws[0], P);
        atomicAdd(&ws[1], E);
        atomicAdd(&ws[2], A);
        atomicAdd(&ws[3], G);
        __threadfence();
        unsigned int* cnt = (unsigned int*)&ws[4];
        const unsigned int old = atomicAdd(cnt, 1u);
        if (old == (unsigned int)(gridDim.x - 1)) {
            // Trailing block: device-scope atomic reads for cross-XCD coherence
            const float npos = atomicAdd(&ws[0], 0.0f);
            const float sce  = atomicAdd(&ws[1], 0.0f);
            const float sac  = atomicAdd(&ws[2], 0.0f);
            const float srg  = atomicAdd(&ws[3], 0.0f);
            const float denom = fmaxf(npos, 1.0f);
            const bool  hp = npos > 0.0f;
            out[0] = hp ? sce / denom : 0.0f;   // cls_loss
            out[1] = hp ? srg / denom : 0.0f;   // reg_loss
            out[2] = hp ? sac / denom : 0.0f;   // acc
        }
    }
}

extern "C" void kernel_launch(void* const* d_in, const int* in_sizes, int n_in,
                              void* d_out, int out_size, void* d_ws, size_t ws_size,
                              hipStream_t stream) {
    const float* nms_reg  = (const float*)d_in[0];
    // d_in[1] = nms_cls, unused by forward
    const float* rcnn_reg = (const float*)d_in[2];
    const float* rcnn_cls = (const float*)d_in[3];
    const float* bboxes   = (const float*)d_in[4];
    const int*   classes  = (const int*)d_in[5];
    float* ws  = (float*)d_ws;
    float* out = (float*)d_out;

    hipMemsetAsync(ws, 0, 8 * sizeof(float), stream);  // sums + counter
    rcnn_main_kernel<<<NBLOCKS, BLK, 0, stream>>>(
        nms_reg, rcnn_reg, rcnn_cls, bboxes, classes, ws, out);
}

// Round 4
// 134.581 us; speedup vs baseline: 1.5913x; 1.5913x over previous
//
#include <hip/hip_runtime.h>

// Problem constants (match reference)
#define BB 32
#define TT 200
#define RR 4096
#define CC 81
#define IOU_THRESH 0.7f
#define RED 16.0f

#define BLK 256
#define NBLOCKS (BB * (RR / BLK))   // 32 * 16 = 512

// ws layout (floats): [0]=npos, [1]=sum_ce, [2]=sum_acc, [3]=sum_reg, [4]=block counter (uint)
__global__ __launch_bounds__(BLK, 1) void rcnn_main_kernel(
    const float* __restrict__ nms_reg,   // [B,R,4]
    const float* __restrict__ rcnn_reg,  // [B,R,4]
    const float* __restrict__ rcnn_cls,  // [B,R,C]
    const float* __restrict__ bboxes,    // [B,T,4]
    const int*   __restrict__ classes,   // [B,T]
    float* __restrict__ ws,
    float* __restrict__ out)
{
    __shared__ float4 s_box[TT];    // GT boxes (ds_read_b128 broadcast)
    __shared__ float  s_area[TT];   // precomputed GT areas
    __shared__ int    s_cls[TT];
    __shared__ float  s_red[4][4];  // [wave][component]

    const int tid  = threadIdx.x;
    const int lane = tid & 63;
    const int blocks_per_b = RR / BLK;              // 16
    const int b = blockIdx.x / blocks_per_b;
    const int r = (blockIdx.x % blocks_per_b) * BLK + tid;
    const long gid = (long)b * RR + r;

    // Stage GT boxes + areas + classes into LDS
    const float4* __restrict__ gbox = (const float4*)(bboxes + (long)b * TT * 4);
    for (int i = tid; i < TT; i += BLK) {
        const float4 g = gbox[i];
        s_box[i]  = g;
        s_area[i] = (g.z - g.x) * (g.w - g.y);
        s_cls[i]  = classes[b * TT + i];
    }
    __syncthreads();

    // Proposal box (coalesced)
    const float4 a = ((const float4*)nms_reg)[gid];
    const float area_a = (a.z - a.x) * (a.w - a.y);

    // Rational running-argmax over T (no divide): best iou = bn/bd, bd > 0.
    float bn = -1.0f, bd = 1.0f;
    int   bt = 0;
    #pragma unroll 8
    for (int t = 0; t < TT; ++t) {
        const float4 g = s_box[t];
        const float it = fmaxf(a.x, g.x);
        const float il = fmaxf(a.y, g.y);
        const float ib = fminf(a.z, g.z);
        const float ir = fminf(a.w, g.w);
        const float inter = fmaxf(ib - it, 0.0f) * fmaxf(ir - il, 0.0f);
        const float uni   = area_a + s_area[t] - inter;
        // inter/uni > bn/bd  <=>  inter*bd > bn*uni   (uni,bd > 0); strict > = first max
        const bool better = inter * bd > bn * uni;
        bn = better ? inter : bn;
        bd = better ? uni   : bd;
        bt = better ? t     : bt;
    }

    // mask: iou > 0.7  <=>  inter > 0.7 * union
    const float pos = (bn > IOU_THRESH * bd) ? 1.0f : 0.0f;
    float ce = 0.0f, acc = 0.0f, reg = 0.0f;

    // Wave-uniform skip: only waves containing a positive touch rcnn_cls.
    // Inside, ALL lanes compute (no exec divergence); results masked by `pos`.
    if (__ballot(pos > 0.5f) != 0ull) {
        const int cls = s_cls[bt];

        // ---- CE + accuracy over C=81: row loaded once into registers ----
        const float* __restrict__ row = rcnn_cls + gid * CC;
        float x[CC];
        #pragma unroll
        for (int c = 0; c < CC; ++c) x[c] = row[c];

        float m = x[0];
        int amax = 0;
        #pragma unroll
        for (int c = 1; c < CC; ++c) {
            if (x[c] > m) { m = x[c]; amax = c; }  // strict > -> first max (jnp.argmax)
        }
        float s = 0.0f;
        #pragma unroll
        for (int c = 0; c < CC; ++c) s += __expf(x[c] - m);
        const float xc = row[cls];                 // avoid dynamic reg-array index
        ce  = (m + __logf(s) - xc) * pos;
        acc = (amax == cls) ? pos : 0.0f;

        // ---- regression target + SmoothL1 (summed over 4 coords) ----
        const float4 g  = s_box[bt];
        const float4 pr = ((const float4*)rcnn_reg)[gid];
        const float rt = rintf(g.x / RED) * RED;   // round-half-even == jnp.round
        const float rl = rintf(g.y / RED) * RED;
        const float rb = rintf(g.z / RED) * RED;
        const float rr = rintf(g.w / RED) * RED;
        float h = rb - rt; if (h == 0.0f) h = 1.0f;
        float w = rr - rl; if (w == 0.0f) w = 1.0f;
        const float d0 = fabsf(pr.x - (g.x - rt) / h);
        const float d1 = fabsf(pr.y - (g.y - rl) / w);
        const float d2 = fabsf(pr.z - (g.z - rb) / h);
        const float d3 = fabsf(pr.w - (g.w - rr) / w);
        float sl  = (d0 < 1.0f) ? 0.5f * d0 * d0 : d0 - 0.5f;
        sl += (d1 < 1.0f) ? 0.5f * d1 * d1 : d1 - 0.5f;
        sl += (d2 < 1.0f) ? 0.5f * d2 * d2 : d2 - 0.5f;
        sl += (d3 < 1.0f) ? 0.5f * d3 * d3 : d3 - 0.5f;
        reg = sl * pos;
    }

    // ---- wave (64-lane) shuffle reduction ----
    float p4 = pos, e4 = ce, a4 = acc, g4 = reg;
    #pragma unroll
    for (int off = 32; off > 0; off >>= 1) {
        p4 += __shfl_down(p4, off);
        e4 += __shfl_down(e4, off);
        a4 += __shfl_down(a4, off);
        g4 += __shfl_down(g4, off);
    }
    const int wave = tid >> 6;
    if (lane == 0) {
        s_red[wave][0] = p4;
        s_red[wave][1] = e4;
        s_red[wave][2] = a4;
        s_red[wave][3] = g4;
    }
    __syncthreads();
    if (tid == 0) {
        float P = 0.0f, E = 0.0f, A = 0.0f, G = 0.0f;
        #pragma unroll
        for (int v = 0; v < 4; ++v) {
            P += s_red[v][0];
            E += s_red[v][1];
            A += s_red[v][2];
            G += s_red[v][3];
        }
        atomicAdd(&ws[0], P);
        atomicAdd(&ws[1], E);
        atomicAdd(&ws[2], A);
        atomicAdd(&ws[3], G);
        __threadfence();
        unsigned int* cnt = (unsigned int*)&ws[4];
        const unsigned int old = atomicAdd(cnt, 1u);
        if (old == (unsigned int)(gridDim.x - 1)) {
            // Trailing block: device-scope atomic reads for cross-XCD coherence
            const float npos = atomicAdd(&ws[0], 0.0f);
            const float sce  = atomicAdd(&ws[1], 0.0f);
            const float sac  = atomicAdd(&ws[2], 0.0f);
            const float srg  = atomicAdd(&ws[3], 0.0f);
            const float denom = fmaxf(npos, 1.0f);
            const bool  hp = npos > 0.0f;
            out[0] = hp ? sce / denom : 0.0f;   // cls_loss
            out[1] = hp ? srg / denom : 0.0f;   // reg_loss
            out[2] = hp ? sac / denom : 0.0f;   // acc
        }
    }
}

extern "C" void kernel_launch(void* const* d_in, const int* in_sizes, int n_in,
                              void* d_out, int out_size, void* d_ws, size_t ws_size,
                              hipStream_t stream) {
    const float* nms_reg  = (const float*)d_in[0];
    // d_in[1] = nms_cls, unused by forward
    const float* rcnn_reg = (const float*)d_in[2];
    const float* rcnn_cls = (const float*)d_in[3];
    const float* bboxes   = (const float*)d_in[4];
    const int*   classes  = (const int*)d_in[5];
    float* ws  = (float*)d_ws;
    float* out = (float*)d_out;

    hipMemsetAsync(ws, 0, 8 * sizeof(float), stream);  // sums + counter
    rcnn_main_kernel<<<NBLOCKS, BLK, 0, stream>>>(
        nms_reg, rcnn_reg, rcnn_cls, bboxes, classes, ws, out);
}

// Round 5
// 132.727 us; speedup vs baseline: 1.6136x; 1.0140x over previous
//
#include <hip/hip_runtime.h>

// Problem constants (match reference)
#define BB 32
#define TT 200
#define RR 4096
#define CC 81
#define IOU_THRESH 0.7f
#define RED 16.0f

#define BLK 256
#define NB (BB * (RR / BLK))   // 512 blocks for both kernels

// ws layout (bytes):
//   [0..3]     uint  done-counter for kernel2 trailing block   (zeroed by k1 block 0)
//   [4..7]     float ce accumulator                            (zeroed by k1 block 0)
//   [8..11]    float acc accumulator                           (zeroed by k1 block 0)
//   [16 .. 16+NB*8)   float2 per-block (npos, reg) partials from kernel1
//   [8192 .. 8192+B*R) uchar flags: bt+1 for positives, 0 otherwise
#define WS_PART_OFF 16
#define WS_FLAG_OFF 8192

__global__ __launch_bounds__(BLK) void rcnn_k1(
    const float* __restrict__ nms_reg,   // [B,R,4]
    const float* __restrict__ rcnn_reg,  // [B,R,4]
    const float* __restrict__ bboxes,    // [B,T,4]
    unsigned char* __restrict__ ws)
{
    __shared__ float4 s_box[TT];
    __shared__ float  s_red[4][2];

    const int tid  = threadIdx.x;
    const int lane = tid & 63;
    const int blocks_per_b = RR / BLK;              // 16
    const int b = blockIdx.x / blocks_per_b;
    const int r = (blockIdx.x % blocks_per_b) * BLK + tid;
    const long gid = (long)b * RR + r;

    // Stage GT boxes into LDS (ds_read_b128 broadcast in the hot loop)
    const float4* __restrict__ gbox = (const float4*)(bboxes + (long)b * TT * 4);
    for (int i = tid; i < TT; i += BLK) s_box[i] = gbox[i];
    __syncthreads();

    const float4 a = ((const float4*)nms_reg)[gid];
    const float area_a = (a.z - a.x) * (a.w - a.y);

    // Rational running-argmax over T (no divide): best iou = bn/bd, bd > 0.
    float bn = -1.0f, bd = 1.0f;
    int   bt = 0;
    #pragma unroll 8
    for (int t = 0; t < TT; ++t) {
        const float4 g = s_box[t];
        const float it = fmaxf(a.x, g.x);
        const float il = fmaxf(a.y, g.y);
        const float ib = fminf(a.z, g.z);
        const float ir = fminf(a.w, g.w);
        const float inter = fmaxf(ib - it, 0.0f) * fmaxf(ir - il, 0.0f);
        const float uni   = area_a + (g.z - g.x) * (g.w - g.y) - inter;
        // inter/uni > bn/bd  <=>  inter*bd > bn*uni  (uni,bd>0); strict > = first max
        const bool better = inter * bd > bn * uni;
        bn = better ? inter : bn;
        bd = better ? uni   : bd;
        bt = better ? t     : bt;
    }

    // mask: iou > 0.7  <=>  inter > 0.7 * union
    const bool ispos = (bn > IOU_THRESH * bd);
    float pos = 0.0f, reg = 0.0f;
    unsigned char flag = 0;
    if (ispos) {
        pos  = 1.0f;
        flag = (unsigned char)(bt + 1);              // bt < 200 fits in u8

        // ---- regression target + SmoothL1 (summed over 4 coords) ----
        const float4 g  = s_box[bt];
        const float4 pr = ((const float4*)rcnn_reg)[gid];
        const float rt = rintf(g.x / RED) * RED;     // round-half-even == jnp.round
        const float rl = rintf(g.y / RED) * RED;
        const float rb = rintf(g.z / RED) * RED;
        const float rr = rintf(g.w / RED) * RED;
        float h = rb - rt; if (h == 0.0f) h = 1.0f;
        float w = rr - rl; if (w == 0.0f) w = 1.0f;
        const float d0 = fabsf(pr.x - (g.x - rt) / h);
        const float d1 = fabsf(pr.y - (g.y - rl) / w);
        const float d2 = fabsf(pr.z - (g.z - rb) / h);
        const float d3 = fabsf(pr.w - (g.w - rr) / w);
        reg  = (d0 < 1.0f) ? 0.5f * d0 * d0 : d0 - 0.5f;
        reg += (d1 < 1.0f) ? 0.5f * d1 * d1 : d1 - 0.5f;
        reg += (d2 < 1.0f) ? 0.5f * d2 * d2 : d2 - 0.5f;
        reg += (d3 < 1.0f) ? 0.5f * d3 * d3 : d3 - 0.5f;
    }
    // Unconditional coalesced flag store (64 B/wave) -> no init needed
    (ws + WS_FLAG_OFF)[gid] = flag;

    // ---- wave + block reduction of (pos, reg) -> per-block partial slots ----
    #pragma unroll
    for (int off = 32; off > 0; off >>= 1) {
        pos += __shfl_down(pos, off);
        reg += __shfl_down(reg, off);
    }
    const int wave = tid >> 6;
    if (lane == 0) { s_red[wave][0] = pos; s_red[wave][1] = reg; }
    __syncthreads();
    if (tid == 0) {
        float P = 0.0f, G = 0.0f;
        #pragma unroll
        for (int v = 0; v < 4; ++v) { P += s_red[v][0]; G += s_red[v][1]; }
        float2* part = (float2*)(ws + WS_PART_OFF);
        part[blockIdx.x] = make_float2(P, G);        // unconditional write, no init
        if (blockIdx.x == 0) {
            // zero kernel2's counter + accumulators (safe: no k1 block touches them,
            // and the kernel boundary orders these before any k2 access)
            *(unsigned int*)ws = 0u;
            *(float*)(ws + 4) = 0.0f;
            *(float*)(ws + 8) = 0.0f;
        }
    }
}

__global__ __launch_bounds__(BLK) void rcnn_k2(
    const float* __restrict__ rcnn_cls,  // [B,R,C]
    const int*   __restrict__ classes,   // [B,T]
    unsigned char* __restrict__ ws,
    float* __restrict__ out)
{
    __shared__ float s_red[4][2];
    __shared__ int   s_last;

    const int tid  = threadIdx.x;
    const int lane = tid & 63;
    const int blocks_per_b = RR / BLK;              // 16
    const int b = blockIdx.x / blocks_per_b;
    const int r = (blockIdx.x % blocks_per_b) * BLK + tid;
    const long gid = (long)b * RR + r;

    const int f = (ws + WS_FLAG_OFF)[gid];          // coalesced u8 load
    float ce = 0.0f, acc = 0.0f;
    if (f != 0) {
        const int bt  = f - 1;
        const int cls = classes[b * TT + bt];
        const float* __restrict__ row = rcnn_cls + gid * CC;

        // Fully unrolled batched loads -> pipelined in the vmcnt queue
        float x[CC];
        #pragma unroll
        for (int c = 0; c < CC; ++c) x[c] = row[c];

        float m = x[0];
        int amax = 0;
        #pragma unroll
        for (int c = 1; c < CC; ++c) {
            if (x[c] > m) { m = x[c]; amax = c; }   // strict > = first max (jnp.argmax)
        }
        float s = 0.0f;
        #pragma unroll
        for (int c = 0; c < CC; ++c) s += __expf(x[c] - m);
        const float xc = row[cls];                   // avoid dynamic reg indexing (L1 hit)
        ce  = m + __logf(s) - xc;
        acc = (amax == cls) ? 1.0f : 0.0f;
    }

    // ---- wave + block reduction ----
    #pragma unroll
    for (int off = 32; off > 0; off >>= 1) {
        ce  += __shfl_down(ce,  off);
        acc += __shfl_down(acc, off);
    }
    const int wave = tid >> 6;
    if (lane == 0) { s_red[wave][0] = ce; s_red[wave][1] = acc; }
    __syncthreads();

    float* ws_ce  = (float*)(ws + 4);
    float* ws_acc = (float*)(ws + 8);
    if (tid == 0) {
        float E = 0.0f, A = 0.0f;
        #pragma unroll
        for (int v = 0; v < 4; ++v) { E += s_red[v][0]; A += s_red[v][1]; }
        atomicAdd(ws_ce,  E);
        atomicAdd(ws_acc, A);
        __threadfence();
        const unsigned int old = atomicAdd((unsigned int*)ws, 1u);
        s_last = (old == (unsigned int)(gridDim.x - 1)) ? 1 : 0;
    }
    __syncthreads();

    if (s_last) {
        // Trailing block: sum kernel1 partials (visible via kernel boundary)
        const float2* part = (const float2*)(ws + WS_PART_OFF);
        float np = 0.0f, rg = 0.0f;
        for (int i = tid; i < NB; i += BLK) {
            const float2 p = part[i];
            np += p.x; rg += p.y;
        }
        #pragma unroll
        for (int off = 32; off > 0; off >>= 1) {
            np += __shfl_down(np, off);
            rg += __shfl_down(rg, off);
        }
        if (lane == 0) { s_red[wave][0] = np; s_red[wave][1] = rg; }
        __syncthreads();
        if (tid == 0) {
            float P = 0.0f, G = 0.0f;
            #pragma unroll
            for (int v = 0; v < 4; ++v) { P += s_red[v][0]; G += s_red[v][1]; }
            // device-scope atomic reads for cross-XCD coherence of k2 accumulators
            const float sce = atomicAdd(ws_ce,  0.0f);
            const float sac = atomicAdd(ws_acc, 0.0f);
            const float denom = fmaxf(P, 1.0f);
            const bool  hp = P > 0.0f;
            out[0] = hp ? sce / denom : 0.0f;   // cls_loss
            out[1] = hp ? G   / denom : 0.0f;   // reg_loss
            out[2] = hp ? sac / denom : 0.0f;   // acc
        }
    }
}

extern "C" void kernel_launch(void* const* d_in, const int* in_sizes, int n_in,
                              void* d_out, int out_size, void* d_ws, size_t ws_size,
                              hipStream_t stream) {
    const float* nms_reg  = (const float*)d_in[0];
    // d_in[1] = nms_cls, unused by forward
    const float* rcnn_reg = (const float*)d_in[2];
    const float* rcnn_cls = (const float*)d_in[3];
    const float* bboxes   = (const float*)d_in[4];
    const int*   classes  = (const int*)d_in[5];
    unsigned char* ws = (unsigned char*)d_ws;
    float* out = (float*)d_out;

    rcnn_k1<<<NB, BLK, 0, stream>>>(nms_reg, rcnn_reg, bboxes, ws);
    rcnn_k2<<<NB, BLK, 0, stream>>>(rcnn_cls, classes, ws, out);
}